// Round 3
// baseline (164.563 us; speedup 1.0000x reference)
//
#include <hip/hip_runtime.h>

#define NTYPES 11
#define BLOCK  256
#define ITEMS  16
#define CHUNK  (BLOCK * ITEMS)   // 4096 atoms per block

// ---------------------------------------------------------------------------
// Kernel 1: per-block per-type histogram.
// bc[t*B + b] = number of atoms of type t in block b's chunk.
// ---------------------------------------------------------------------------
__global__ __launch_bounds__(BLOCK) void hist_kernel(
    const int* __restrict__ types, int N, int B, int* __restrict__ bc) {
  __shared__ int shCnt[NTYPES];
  const int tid = threadIdx.x;
  const int b = blockIdx.x;
  if (tid < NTYPES) shCnt[tid] = 0;
  __syncthreads();

  const int run = b * CHUNK + tid * ITEMS;
  int cnt[NTYPES];
#pragma unroll
  for (int t = 0; t < NTYPES; ++t) cnt[t] = 0;

  if (run < N) {
    const int* p = types + run;
    int ty[ITEMS];
#pragma unroll
    for (int k = 0; k < ITEMS; ++k) ty[k] = __builtin_nontemporal_load(p + k);
#pragma unroll
    for (int k = 0; k < ITEMS; ++k) {
#pragma unroll
      for (int t = 0; t < NTYPES; ++t) cnt[t] += (ty[k] == t) ? 1 : 0;
    }
  }

  const int lane = tid & 63;
#pragma unroll
  for (int t = 0; t < NTYPES; ++t) {
    int v = cnt[t];
    for (int o = 32; o >= 1; o >>= 1) v += __shfl_down(v, o);
    if (lane == 0) atomicAdd(&shCnt[t], v);
  }
  __syncthreads();
  if (tid < NTYPES) bc[tid * B + b] = shCnt[tid];
}

// ---------------------------------------------------------------------------
// Kernel 2: one block, 11 waves. Wave t scans type t's block-counts (B <=
// 1024) in 16 chunks of 64 with a register carry — no inter-wave sync until
// the tiny epilogue. Writes counts/offsets as FLOATS into the tail of d_out.
// ---------------------------------------------------------------------------
__global__ __launch_bounds__(NTYPES * 64) void scan_kernel(
    const int* __restrict__ bc, int B, int* __restrict__ scanOut,
    int* __restrict__ offs, float* __restrict__ outTail) {
  __shared__ int totals[NTYPES];
  const int lane = threadIdx.x & 63;
  const int t = threadIdx.x >> 6;  // wave index == type

  int carry = 0;
#pragma unroll
  for (int cchunk = 0; cchunk < 16; ++cchunk) {
    const int idx = cchunk * 64 + lane;
    const int x = (idx < B) ? bc[t * B + idx] : 0;
    int incl = x;
#pragma unroll
    for (int o = 1; o < 64; o <<= 1) {
      int v = __shfl_up(incl, o);
      if (lane >= o) incl += v;
    }
    incl += carry;
    if (idx < B) scanOut[t * B + idx] = incl - x;
    carry = __shfl(incl, 63);
    if (cchunk * 64 + 64 >= B && cchunk * 64 < B) break;  // early out past B
  }
  if (lane == 0) totals[t] = carry;
  __syncthreads();

  if (threadIdx.x == 0) {
    int off = 0;
    for (int u = 0; u < NTYPES; ++u) {
      const int c = totals[u];
      offs[u] = off;
      outTail[u] = (float)c;            // counts (as float values)
      outTail[NTYPES + u] = (float)off; // offsets (as float values)
      off += c;
    }
  }
}

// ---------------------------------------------------------------------------
// Kernel 3: stable scatter with LDS bucket staging.
// Phase 1: rank each atom within the block (stable), scatter its coords into
//          a type-sorted LDS buffer.
// Phase 2: copy LDS -> global. Each type's segment is contiguous in global
//          memory, so consecutive lanes write consecutive 12B triplets.
// ---------------------------------------------------------------------------
__global__ __launch_bounds__(BLOCK) void scatter_kernel(
    const float* __restrict__ coords, const int* __restrict__ types,
    const int* __restrict__ scanOut, const int* __restrict__ offs, int N,
    int B, float* __restrict__ out) {
  __shared__ float shC[CHUNK * 3];      // 48 KB type-sorted coords
  __shared__ int wtot[NTYPES][4];       // per-wave inclusive totals
  __shared__ int shOff[NTYPES + 1];     // local bucket offsets (exclusive)
  __shared__ int shDelta[NTYPES];       // 3*(globalBase[t] - shOff[t])

  const int tid = threadIdx.x;
  const int b = blockIdx.x;
  const int lane = tid & 63;
  const int wave = tid >> 6;
  const int run = b * CHUNK + tid * ITEMS;
  const bool active = (run < N);

  int ty[ITEMS];
  int cnt[NTYPES];
#pragma unroll
  for (int t = 0; t < NTYPES; ++t) cnt[t] = 0;
#pragma unroll
  for (int k = 0; k < ITEMS; ++k) ty[k] = -1;

  float c[ITEMS * 3];
  if (active) {
    const int* p = types + run;
#pragma unroll
    for (int k = 0; k < ITEMS; ++k) ty[k] = __builtin_nontemporal_load(p + k);
    const float* cp = coords + (size_t)run * 3;
#pragma unroll
    for (int q = 0; q < ITEMS * 3; ++q)
      c[q] = __builtin_nontemporal_load(cp + q);
#pragma unroll
    for (int k = 0; k < ITEMS; ++k) {
#pragma unroll
      for (int t = 0; t < NTYPES; ++t) cnt[t] += (ty[k] == t) ? 1 : 0;
    }
  }

  // Wave-level stable exclusive scan per type.
  int rank[NTYPES];
#pragma unroll
  for (int t = 0; t < NTYPES; ++t) {
    int incl = cnt[t];
#pragma unroll
    for (int o = 1; o < 64; o <<= 1) {
      int v = __shfl_up(incl, o);
      if (lane >= o) incl += v;
    }
    if (lane == 63) wtot[t][wave] = incl;
    rank[t] = incl - cnt[t];  // exclusive within wave
  }
  __syncthreads();

  // Local bucket offsets + global deltas (threads 0..NTYPES-1).
  if (tid < NTYPES) {
    int loc = 0;
    for (int u = 0; u < tid; ++u)
      loc += wtot[u][0] + wtot[u][1] + wtot[u][2] + wtot[u][3];
    shOff[tid] = loc;
    shDelta[tid] = 3 * (offs[tid] + scanOut[tid * B + b] - loc);
    if (tid == NTYPES - 1) {
      shOff[NTYPES] =
          loc + wtot[tid][0] + wtot[tid][1] + wtot[tid][2] + wtot[tid][3];
    }
  }
  __syncthreads();

  // Finalize local ranks: bucket base + wave base + lane-exclusive.
#pragma unroll
  for (int t = 0; t < NTYPES; ++t) {
    int wb = 0;
#pragma unroll
    for (int w = 0; w < 3; ++w) wb += (w < wave) ? wtot[t][w] : 0;
    rank[t] += wb + shOff[t];
  }

  // Scatter coords into type-sorted LDS buffer.
  if (active) {
#pragma unroll
    for (int k = 0; k < ITEMS; ++k) {
      const int t0 = ty[k];
      int slot = 0;
#pragma unroll
      for (int t = 0; t < NTYPES; ++t) {
        if (t0 == t) {
          slot = rank[t];
          rank[t] += 1;
        }
      }
      shC[3 * slot + 0] = c[3 * k + 0];
      shC[3 * slot + 1] = c[3 * k + 1];
      shC[3 * slot + 2] = c[3 * k + 2];
    }
  }
  __syncthreads();

  // Coalesced copy-out: slot s -> global float index 3*s + delta3[type(s)].
  const int total = shOff[NTYPES];
  int offr[NTYPES];
  int dlt[NTYPES];
#pragma unroll
  for (int t = 0; t < NTYPES; ++t) {
    offr[t] = shOff[t];
    dlt[t] = shDelta[t];
  }
#pragma unroll
  for (int k = 0; k < ITEMS; ++k) {
    const int s = k * BLOCK + tid;
    if (s < total) {
      int d = dlt[0];
#pragma unroll
      for (int t = 1; t < NTYPES; ++t) d = (s >= offr[t]) ? dlt[t] : d;
      const int src = 3 * s;
      out[src + d + 0] = shC[src + 0];
      out[src + d + 1] = shC[src + 1];
      out[src + d + 2] = shC[src + 2];
    }
  }
}

extern "C" void kernel_launch(void* const* d_in, const int* in_sizes, int n_in,
                              void* d_out, int out_size, void* d_ws,
                              size_t ws_size, hipStream_t stream) {
  const float* coords = (const float*)d_in[0];
  const int* types = (const int*)d_in[1];
  const int N = in_sizes[1];              // 4,000,000 atoms
  const int B = (N + CHUNK - 1) / CHUNK;  // 977 blocks

  int* bc = (int*)d_ws;              // [NTYPES * B]
  int* scanOut = bc + NTYPES * B;    // [NTYPES * B]
  int* offs = scanOut + NTYPES * B;  // [NTYPES]
  float* out = (float*)d_out;
  float* outTail = out + (size_t)3 * N;  // counts then offsets, as floats

  hist_kernel<<<B, BLOCK, 0, stream>>>(types, N, B, bc);
  scan_kernel<<<1, NTYPES * 64, 0, stream>>>(bc, B, scanOut, offs, outTail);
  scatter_kernel<<<B, BLOCK, 0, stream>>>(coords, types, scanOut, offs, N, B,
                                          out);
}

// Round 4
// 133.968 us; speedup vs baseline: 1.2284x; 1.2284x over previous
//
#include <hip/hip_runtime.h>

#define NTYPES 11
#define BLOCK  256
#define ITEMS  8
#define CHUNK  (BLOCK * ITEMS)   // 2048 atoms per block
#define MAXCH  32                // max scan chunks (B <= 2048)

// ---------------------------------------------------------------------------
// Kernel 1: per-block per-type histogram.
// bc[t*B + b] = number of atoms of type t in block b's chunk.
// ---------------------------------------------------------------------------
__global__ __launch_bounds__(BLOCK) void hist_kernel(
    const int* __restrict__ types, int N, int B, int* __restrict__ bc) {
  __shared__ int shCnt[NTYPES];
  const int tid = threadIdx.x;
  const int b = blockIdx.x;
  if (tid < NTYPES) shCnt[tid] = 0;
  __syncthreads();

  const int run = b * CHUNK + tid * ITEMS;
  int cnt[NTYPES];
#pragma unroll
  for (int t = 0; t < NTYPES; ++t) cnt[t] = 0;

  if (run < N) {
    const int4* p = (const int4*)(types + run);
    int4 a0 = p[0], a1 = p[1];
    int ty[ITEMS] = {a0.x, a0.y, a0.z, a0.w, a1.x, a1.y, a1.z, a1.w};
#pragma unroll
    for (int k = 0; k < ITEMS; ++k) {
#pragma unroll
      for (int t = 0; t < NTYPES; ++t) cnt[t] += (ty[k] == t) ? 1 : 0;
    }
  }

  const int lane = tid & 63;
#pragma unroll
  for (int t = 0; t < NTYPES; ++t) {
    int v = cnt[t];
    for (int o = 32; o >= 1; o >>= 1) v += __shfl_down(v, o);
    if (lane == 0) atomicAdd(&shCnt[t], v);
  }
  __syncthreads();
  if (tid < NTYPES) bc[tid * B + b] = shCnt[tid];
}

// ---------------------------------------------------------------------------
// Kernel 2: one block, 11 waves; wave t scans type t's block-counts.
// All chunk values preloaded into registers (independent loads overlap),
// then a register-carry shfl scan. Requires B <= 2048.
// ---------------------------------------------------------------------------
__global__ __launch_bounds__(NTYPES * 64) void scan_kernel(
    const int* __restrict__ bc, int B, int* __restrict__ scanOut,
    int* __restrict__ offs, float* __restrict__ outTail) {
  __shared__ int totals[NTYPES];
  const int lane = threadIdx.x & 63;
  const int t = threadIdx.x >> 6;  // wave index == type
  const int nch = (B + 63) >> 6;

  int x[MAXCH];
#pragma unroll
  for (int c = 0; c < MAXCH; ++c) {
    const int idx = c * 64 + lane;
    x[c] = (c < nch && idx < B) ? bc[t * B + idx] : 0;
  }

  int carry = 0;
#pragma unroll
  for (int c = 0; c < MAXCH; ++c) {
    if (c >= nch) break;
    int incl = x[c];
#pragma unroll
    for (int o = 1; o < 64; o <<= 1) {
      int v = __shfl_up(incl, o);
      if (lane >= o) incl += v;
    }
    incl += carry;
    const int idx = c * 64 + lane;
    if (idx < B) scanOut[t * B + idx] = incl - x[c];
    carry = __shfl(incl, 63);
  }
  if (lane == 0) totals[t] = carry;
  __syncthreads();

  if (threadIdx.x == 0) {
    int off = 0;
    for (int u = 0; u < NTYPES; ++u) {
      const int c = totals[u];
      offs[u] = off;
      outTail[u] = (float)c;            // counts (as float values)
      outTail[NTYPES + u] = (float)off; // offsets (as float values)
      off += c;
    }
  }
}

// ---------------------------------------------------------------------------
// Kernel 3: stable scatter with LDS bucket staging (24 KB -> 6 blocks/CU).
// Phase 1: stable in-block rank, scatter coords into type-sorted LDS.
// Phase 2: coalesced copy-out; each type's segment is contiguous in global.
// ---------------------------------------------------------------------------
__global__ __launch_bounds__(BLOCK) void scatter_kernel(
    const float* __restrict__ coords, const int* __restrict__ types,
    const int* __restrict__ scanOut, const int* __restrict__ offs, int N,
    int B, float* __restrict__ out) {
  __shared__ float shC[CHUNK * 3];      // 24 KB type-sorted coords
  __shared__ int wtot[NTYPES][4];       // per-wave inclusive totals
  __shared__ int shOff[NTYPES + 1];     // local bucket offsets (exclusive)
  __shared__ int shDelta[NTYPES];       // 3*(globalBase[t] - shOff[t])

  const int tid = threadIdx.x;
  const int b = blockIdx.x;
  const int lane = tid & 63;
  const int wave = tid >> 6;
  const int run = b * CHUNK + tid * ITEMS;
  const bool active = (run < N);

  int ty[ITEMS];
  int cnt[NTYPES];
#pragma unroll
  for (int t = 0; t < NTYPES; ++t) cnt[t] = 0;
#pragma unroll
  for (int k = 0; k < ITEMS; ++k) ty[k] = -1;

  float c[ITEMS * 3];
  if (active) {
    const int4* p = (const int4*)(types + run);
    int4 a0 = p[0], a1 = p[1];
    int tt[ITEMS] = {a0.x, a0.y, a0.z, a0.w, a1.x, a1.y, a1.z, a1.w};
#pragma unroll
    for (int k = 0; k < ITEMS; ++k) ty[k] = tt[k];
    const float4* cp = (const float4*)(coords + (size_t)run * 3);
#pragma unroll
    for (int q = 0; q < (ITEMS * 3) / 4; ++q) {
      float4 v = cp[q];
      c[4 * q + 0] = v.x;
      c[4 * q + 1] = v.y;
      c[4 * q + 2] = v.z;
      c[4 * q + 3] = v.w;
    }
#pragma unroll
    for (int k = 0; k < ITEMS; ++k) {
#pragma unroll
      for (int t = 0; t < NTYPES; ++t) cnt[t] += (ty[k] == t) ? 1 : 0;
    }
  }

  // Wave-level stable exclusive scan per type.
  int rank[NTYPES];
#pragma unroll
  for (int t = 0; t < NTYPES; ++t) {
    int incl = cnt[t];
#pragma unroll
    for (int o = 1; o < 64; o <<= 1) {
      int v = __shfl_up(incl, o);
      if (lane >= o) incl += v;
    }
    if (lane == 63) wtot[t][wave] = incl;
    rank[t] = incl - cnt[t];  // exclusive within wave
  }
  __syncthreads();

  // Local bucket offsets + global deltas (threads 0..NTYPES-1).
  if (tid < NTYPES) {
    int loc = 0;
    for (int u = 0; u < tid; ++u)
      loc += wtot[u][0] + wtot[u][1] + wtot[u][2] + wtot[u][3];
    shOff[tid] = loc;
    shDelta[tid] = 3 * (offs[tid] + scanOut[tid * B + b] - loc);
    if (tid == NTYPES - 1) {
      shOff[NTYPES] =
          loc + wtot[tid][0] + wtot[tid][1] + wtot[tid][2] + wtot[tid][3];
    }
  }
  __syncthreads();

  // Finalize local ranks: bucket base + wave base + lane-exclusive.
#pragma unroll
  for (int t = 0; t < NTYPES; ++t) {
    int wb = 0;
#pragma unroll
    for (int w = 0; w < 3; ++w) wb += (w < wave) ? wtot[t][w] : 0;
    rank[t] += wb + shOff[t];
  }

  // Scatter coords into type-sorted LDS buffer.
  if (active) {
#pragma unroll
    for (int k = 0; k < ITEMS; ++k) {
      const int t0 = ty[k];
      int slot = 0;
#pragma unroll
      for (int t = 0; t < NTYPES; ++t) {
        if (t0 == t) {
          slot = rank[t];
          rank[t] += 1;
        }
      }
      shC[3 * slot + 0] = c[3 * k + 0];
      shC[3 * slot + 1] = c[3 * k + 1];
      shC[3 * slot + 2] = c[3 * k + 2];
    }
  }
  __syncthreads();

  // Coalesced copy-out: slot s -> global float index 3*s + delta3[type(s)].
  const int total = shOff[NTYPES];
  int offr[NTYPES];
  int dlt[NTYPES];
#pragma unroll
  for (int t = 0; t < NTYPES; ++t) {
    offr[t] = shOff[t];
    dlt[t] = shDelta[t];
  }
#pragma unroll
  for (int k = 0; k < ITEMS; ++k) {
    const int s = k * BLOCK + tid;
    if (s < total) {
      int d = dlt[0];
#pragma unroll
      for (int t = 1; t < NTYPES; ++t) d = (s >= offr[t]) ? dlt[t] : d;
      const int src = 3 * s;
      out[src + d + 0] = shC[src + 0];
      out[src + d + 1] = shC[src + 1];
      out[src + d + 2] = shC[src + 2];
    }
  }
}

extern "C" void kernel_launch(void* const* d_in, const int* in_sizes, int n_in,
                              void* d_out, int out_size, void* d_ws,
                              size_t ws_size, hipStream_t stream) {
  const float* coords = (const float*)d_in[0];
  const int* types = (const int*)d_in[1];
  const int N = in_sizes[1];              // 4,000,000 atoms
  const int B = (N + CHUNK - 1) / CHUNK;  // 1954 blocks

  int* bc = (int*)d_ws;              // [NTYPES * B]
  int* scanOut = bc + NTYPES * B;    // [NTYPES * B]
  int* offs = scanOut + NTYPES * B;  // [NTYPES]
  float* out = (float*)d_out;
  float* outTail = out + (size_t)3 * N;  // counts then offsets, as floats

  hist_kernel<<<B, BLOCK, 0, stream>>>(types, N, B, bc);
  scan_kernel<<<1, NTYPES * 64, 0, stream>>>(bc, B, scanOut, offs, outTail);
  scatter_kernel<<<B, BLOCK, 0, stream>>>(coords, types, scanOut, offs, N, B,
                                          out);
}